// Round 5
// baseline (580.150 us; speedup 1.0000x reference)
//
#include <hip/hip_runtime.h>

#define USER_COUNT 200000
#define ITEM_COUNT 100000
#define N_NODES    300000   // USER_COUNT + ITEM_COUNT
#define EMB        64
#define BATCH      4096

typedef unsigned int   u32;
typedef unsigned short u16;
typedef u16   ushort8v __attribute__((ext_vector_type(8)));
typedef float float8v  __attribute__((ext_vector_type(8)));

static __device__ __forceinline__ float bf2f(u16 h) {
    return __uint_as_float(((u32)h) << 16);
}
static __device__ __forceinline__ u16 f2bf(float f) {   // round-to-nearest-even
    u32 u = __float_as_uint(f);
    u32 r = (u + 0x7FFFu + ((u >> 16) & 1u)) >> 16;
    return (u16)r;
}

// ---------------------------------------------------------------------------
// row_ptr from sorted COO rows. ptr[r] = first i with row[i] >= r.
// ---------------------------------------------------------------------------
__global__ void build_row_ptr(const int* __restrict__ row,
                              int* __restrict__ ptr, int nnz) {
    int i = blockIdx.x * blockDim.x + threadIdx.x;
    if (i >= nnz) return;
    int r  = row[i];
    int rp = (i == 0) ? -1 : row[i - 1];
    for (int rr = rp + 1; rr <= r; ++rr) ptr[rr] = i;
    if (i == nnz - 1) {
        for (int rr = r + 1; rr <= N_NODES; ++rr) ptr[rr] = nnz;
    }
}

// ---------------------------------------------------------------------------
// ego16 = bf16(concat(user_emb, item_emb)); each thread converts 4 elems.
// ---------------------------------------------------------------------------
__global__ void convert_bf16(const float* __restrict__ ue,
                             const float* __restrict__ ie,
                             u16* __restrict__ out16) {
    size_t t = (size_t)blockIdx.x * blockDim.x + threadIdx.x;
    const size_t total = (size_t)N_NODES * EMB / 4;
    if (t >= total) return;
    size_t base = t * 4;
    const size_t ub = (size_t)USER_COUNT * EMB;
    const float* src = (base < ub) ? (ue + base) : (ie + (base - ub));
    float4 v = *(const float4*)src;
    ushort4 o;
    o.x = f2bf(v.x); o.y = f2bf(v.y); o.z = f2bf(v.z); o.w = f2bf(v.w);
    *(ushort4*)(out16 + base) = o;
}

// ---------------------------------------------------------------------------
// Mark nodes whose h2 row is actually consumed:
//   - the 8192 selected rows themselves (output gather)
//   - cols of the selected rows' edges (layer-3 gathers)
// One wave per selected slot; lanes stride the edge list.
// ---------------------------------------------------------------------------
__global__ void mark_needed(const int* __restrict__ users,
                            const int* __restrict__ items,
                            const int* __restrict__ col,
                            const int* __restrict__ ptr,
                            u32* __restrict__ flag) {
    int slot = (int)((blockIdx.x * blockDim.x + threadIdx.x) >> 6);
    if (slot >= 2 * BATCH) return;
    int lane = threadIdx.x & 63;
    int row = (slot < BATCH) ? users[slot] : (items[slot - BATCH] + USER_COUNT);
    if (lane == 0) flag[row] = 1;
    int p0 = ptr[row];
    int p1 = ptr[row + 1];
    for (int j = p0 + lane; j < p1; j += 64) flag[col[j]] = 1;
}

// ---------------------------------------------------------------------------
// Inner gather-FMA: 8-lane group handles one edge; lane covers 8 bf16 dims.
// ---------------------------------------------------------------------------
#define EDGE_FMA8(J, ACC)                                             \
    {                                                                 \
        int   c = __builtin_nontemporal_load(col + (J));              \
        float v = __builtin_nontemporal_load(val + (J));              \
        ushort8v h8 = *(const ushort8v*)(x + (size_t)c * EMB + d);    \
        _Pragma("unroll")                                             \
        for (int q = 0; q < 8; ++q) ACC[q] += v * bf2f(h8[q]);        \
    }

#define SLOT_REDUCE(ACC)                                              \
    _Pragma("unroll")                                                 \
    for (int q = 0; q < 8; ++q) {                                     \
        ACC[q] += __shfl_xor(ACC[q], 8, 64);                          \
        ACC[q] += __shfl_xor(ACC[q], 16, 64);                         \
        ACC[q] += __shfl_xor(ACC[q], 32, 64);                         \
    }

// ---------------------------------------------------------------------------
// Full SpMM (bf16 in / bf16 out): one wave per row.
//   e = lane>>3 : edge slot (8 concurrent edges); d = (lane&7)*8 dims.
// Unroll x4 -> 32 independent 128B gathers in flight per wave.
// USE_FLAG: skip rows whose output is never consumed.
// ---------------------------------------------------------------------------
template <bool USE_FLAG>
__global__ __launch_bounds__(256) void spmm_bf16(
        const u16* __restrict__ x, const int* __restrict__ col,
        const float* __restrict__ val, const int* __restrict__ ptr,
        const u32* __restrict__ flag, u16* __restrict__ y) {
    int wave = (int)((blockIdx.x * blockDim.x + threadIdx.x) >> 6);
    int lane = threadIdx.x & 63;
    if (wave >= N_NODES) return;
    if (USE_FLAG && flag[wave] == 0) return;
    int e = lane >> 3;          // 0..7
    int d = (lane & 7) << 3;    // 0,8,...,56

    int p0 = ptr[wave];
    int p1 = ptr[wave + 1];

    float8v a0 = {0,0,0,0,0,0,0,0};
    float8v a1 = {0,0,0,0,0,0,0,0};
    float8v a2 = {0,0,0,0,0,0,0,0};
    float8v a3 = {0,0,0,0,0,0,0,0};

    int j = p0 + e;
    for (; j + 24 < p1; j += 32) {
        EDGE_FMA8(j,      a0);
        EDGE_FMA8(j + 8,  a1);
        EDGE_FMA8(j + 16, a2);
        EDGE_FMA8(j + 24, a3);
    }
    if (j < p1) {
        EDGE_FMA8(j, a0);
        if (j + 8 < p1) {
            EDGE_FMA8(j + 8, a1);
            if (j + 16 < p1) EDGE_FMA8(j + 16, a2);
        }
    }

    #pragma unroll
    for (int q = 0; q < 8; ++q) a0[q] += a1[q] + a2[q] + a3[q];

    SLOT_REDUCE(a0);

    if (e == 0) {
        ushort8v o;
        #pragma unroll
        for (int q = 0; q < 8; ++q) o[q] = f2bf(a0[q]);
        *(ushort8v*)(y + (size_t)wave * EMB + d) = o;
    }
}

// ---------------------------------------------------------------------------
// Layer-3 SpMM restricted to the 8192 selected rows, fused with output
// accumulation: out[slot] += 0.25 * (A * x)[row(slot)].
// ---------------------------------------------------------------------------
__global__ __launch_bounds__(256) void spmm_bf16_sel(
        const u16* __restrict__ x, const int* __restrict__ col,
        const float* __restrict__ val, const int* __restrict__ ptr,
        const int* __restrict__ users, const int* __restrict__ items,
        float* __restrict__ out) {
    int slot = (int)((blockIdx.x * blockDim.x + threadIdx.x) >> 6);
    if (slot >= 2 * BATCH) return;
    int lane = threadIdx.x & 63;
    int e = lane >> 3;
    int d = (lane & 7) << 3;

    int row = (slot < BATCH) ? users[slot] : (items[slot - BATCH] + USER_COUNT);
    int p0 = ptr[row];
    int p1 = ptr[row + 1];

    float8v a0 = {0,0,0,0,0,0,0,0};
    float8v a1 = {0,0,0,0,0,0,0,0};

    int j = p0 + e;
    for (; j + 8 < p1; j += 16) {
        EDGE_FMA8(j,     a0);
        EDGE_FMA8(j + 8, a1);
    }
    if (j < p1) EDGE_FMA8(j, a0);

    #pragma unroll
    for (int q = 0; q < 8; ++q) a0[q] += a1[q];

    SLOT_REDUCE(a0);

    if (e == 0) {
        float* o = out + (size_t)slot * EMB + d;
        float4 c0 = *(float4*)o;
        float4 c1 = *(float4*)(o + 4);
        c0.x += 0.25f * a0[0]; c0.y += 0.25f * a0[1];
        c0.z += 0.25f * a0[2]; c0.w += 0.25f * a0[3];
        c1.x += 0.25f * a0[4]; c1.y += 0.25f * a0[5];
        c1.z += 0.25f * a0[6]; c1.w += 0.25f * a0[7];
        *(float4*)o       = c0;
        *(float4*)(o + 4) = c1;
    }
}

// ---------------------------------------------------------------------------
// out = 0.25 * ego[selected]  (exact f32 inputs; first write)
// ---------------------------------------------------------------------------
__global__ void gather_f32(const float* __restrict__ xu,
                           const float* __restrict__ xi,
                           const int* __restrict__ users,
                           const int* __restrict__ items,
                           float* __restrict__ out) {
    int tid = blockIdx.x * blockDim.x + threadIdx.x;
    if (tid >= 2 * BATCH * (EMB / 4)) return;
    int b = tid >> 4;
    int e = (tid & 15) << 2;
    const float* src;
    if (b < BATCH) src = xu + (size_t)users[b] * EMB + e;
    else           src = xi + (size_t)items[b - BATCH] * EMB + e;
    float4 s = *(const float4*)src;
    float4 v = {0.25f * s.x, 0.25f * s.y, 0.25f * s.z, 0.25f * s.w};
    *(float4*)(out + (size_t)b * EMB + e) = v;
}

// ---------------------------------------------------------------------------
// out += 0.25 * h[selected]  (bf16 source)
// ---------------------------------------------------------------------------
__global__ void gather_bf16_add(const u16* __restrict__ h,
                                const int* __restrict__ users,
                                const int* __restrict__ items,
                                float* __restrict__ out) {
    int tid = blockIdx.x * blockDim.x + threadIdx.x;
    if (tid >= 2 * BATCH * (EMB / 4)) return;
    int b = tid >> 4;
    int e = (tid & 15) << 2;
    int row = (b < BATCH) ? users[b] : (items[b - BATCH] + USER_COUNT);
    ushort4 s = *(const ushort4*)(h + (size_t)row * EMB + e);
    float4* o = (float4*)(out + (size_t)b * EMB + e);
    float4 cur = *o;
    cur.x += 0.25f * bf2f(s.x);
    cur.y += 0.25f * bf2f(s.y);
    cur.z += 0.25f * bf2f(s.z);
    cur.w += 0.25f * bf2f(s.w);
    *o = cur;
}

extern "C" void kernel_launch(void* const* d_in, const int* in_sizes, int n_in,
                              void* d_out, int out_size, void* d_ws, size_t ws_size,
                              hipStream_t stream) {
    const float* user_emb = (const float*)d_in[0];
    const float* item_emb = (const float*)d_in[1];
    const int*   adj_row  = (const int*)d_in[2];
    const int*   adj_col  = (const int*)d_in[3];
    const float* adj_val  = (const float*)d_in[4];
    const int*   users    = (const int*)d_in[5];
    const int*   items    = (const int*)d_in[6];
    float*       out      = (float*)d_out;
    const int    nnz      = in_sizes[2];

    char* ws = (char*)d_ws;
    const size_t hbytes = (size_t)N_NODES * EMB * sizeof(u16); // 38.4 MB
    u16* ego16 = (u16*)(ws);
    u16* h1    = (u16*)(ws + hbytes);
    u16* h2    = (u16*)(ws + 2 * hbytes);
    int* ptr   = (int*)(ws + 3 * hbytes);
    u32* flag  = (u32*)(ws + 3 * hbytes + (size_t)(N_NODES + 64) * sizeof(int));

    // 0) clear needed-flags (ws is NOT re-zeroed between timed replays)
    hipMemsetAsync(flag, 0, (size_t)N_NODES * sizeof(u32), stream);

    // 1) row_ptr
    build_row_ptr<<<(nnz + 255) / 256, 256, 0, stream>>>(adj_row, ptr, nnz);

    // 2) ego -> bf16
    {
        const size_t total = (size_t)N_NODES * EMB / 4;
        convert_bf16<<<(unsigned)((total + 255) / 256), 256, 0, stream>>>(
            user_emb, item_emb, ego16);
    }

    // 2b) mark rows whose h2 is consumed
    mark_needed<<<(2 * BATCH + 3) / 4, 256, 0, stream>>>(
        users, items, adj_col, ptr, flag);

    // 3) out = 0.25 * ego[sel]  (exact f32)
    const int gthreads = 2 * BATCH * (EMB / 4);
    gather_f32<<<(gthreads + 255) / 256, 256, 0, stream>>>(
        user_emb, item_emb, users, items, out);

    const int spmm_blocks = (N_NODES + 3) / 4;

    // 4) h1 = A * ego16 ; out += 0.25*h1[sel]
    spmm_bf16<false><<<spmm_blocks, 256, 0, stream>>>(
        ego16, adj_col, adj_val, ptr, nullptr, h1);
    gather_bf16_add<<<(gthreads + 255) / 256, 256, 0, stream>>>(h1, users, items, out);

    // 5) h2 = A * h1 (only needed rows) ; out += 0.25*h2[sel]
    spmm_bf16<true><<<spmm_blocks, 256, 0, stream>>>(
        h1, adj_col, adj_val, ptr, flag, h2);
    gather_bf16_add<<<(gthreads + 255) / 256, 256, 0, stream>>>(h2, users, items, out);

    // 6) out += 0.25 * (A*h2)[sel]   (layer 3 restricted to 8192 rows)
    spmm_bf16_sel<<<(2 * BATCH + 3) / 4, 256, 0, stream>>>(
        h2, adj_col, adj_val, ptr, users, items, out);
}

// Round 6
// 385.279 us; speedup vs baseline: 1.5058x; 1.5058x over previous
//
#include <hip/hip_runtime.h>

#define USER_COUNT 200000
#define ITEM_COUNT 100000
#define N_NODES    300000   // USER_COUNT + ITEM_COUNT
#define EMB        64
#define BATCH      4096

typedef unsigned int   u32;
typedef unsigned short u16;
typedef u16   ushort8v __attribute__((ext_vector_type(8)));
typedef float float8v  __attribute__((ext_vector_type(8)));

static __device__ __forceinline__ float bf2f(u16 h) {
    return __uint_as_float(((u32)h) << 16);
}
static __device__ __forceinline__ u16 f2bf(float f) {   // round-to-nearest-even
    u32 u = __float_as_uint(f);
    u32 r = (u + 0x7FFFu + ((u >> 16) & 1u)) >> 16;
    return (u16)r;
}

// ---------------------------------------------------------------------------
// row_ptr from sorted COO rows. ptr[r] = first i with row[i] >= r.
// ---------------------------------------------------------------------------
__global__ void build_row_ptr(const int* __restrict__ row,
                              int* __restrict__ ptr, int nnz) {
    int i = blockIdx.x * blockDim.x + threadIdx.x;
    if (i >= nnz) return;
    int r  = row[i];
    int rp = (i == 0) ? -1 : row[i - 1];
    for (int rr = rp + 1; rr <= r; ++rr) ptr[rr] = i;
    if (i == nnz - 1) {
        for (int rr = r + 1; rr <= N_NODES; ++rr) ptr[rr] = nnz;
    }
}

// ---------------------------------------------------------------------------
// ego16 = bf16(concat(user_emb, item_emb)); each thread converts 4 elems.
// ---------------------------------------------------------------------------
__global__ void convert_bf16(const float* __restrict__ ue,
                             const float* __restrict__ ie,
                             u16* __restrict__ out16) {
    size_t t = (size_t)blockIdx.x * blockDim.x + threadIdx.x;
    const size_t total = (size_t)N_NODES * EMB / 4;
    if (t >= total) return;
    size_t base = t * 4;
    const size_t ub = (size_t)USER_COUNT * EMB;
    const float* src = (base < ub) ? (ue + base) : (ie + (base - ub));
    float4 v = *(const float4*)src;
    ushort4 o;
    o.x = f2bf(v.x); o.y = f2bf(v.y); o.z = f2bf(v.z); o.w = f2bf(v.w);
    *(ushort4*)(out16 + base) = o;
}

// ---------------------------------------------------------------------------
// Mark nodes whose h2 row is actually consumed:
//   - the 8192 selected rows themselves (output gather)
//   - cols of the selected rows' edges (layer-3 gathers)
// ---------------------------------------------------------------------------
__global__ void mark_needed(const int* __restrict__ users,
                            const int* __restrict__ items,
                            const int* __restrict__ col,
                            const int* __restrict__ ptr,
                            u32* __restrict__ flag) {
    int slot = (int)((blockIdx.x * blockDim.x + threadIdx.x) >> 6);
    if (slot >= 2 * BATCH) return;
    int lane = threadIdx.x & 63;
    int row = (slot < BATCH) ? users[slot] : (items[slot - BATCH] + USER_COUNT);
    if (lane == 0) flag[row] = 1;
    int p0 = ptr[row];
    int p1 = ptr[row + 1];
    for (int j = p0 + lane; j < p1; j += 64) flag[col[j]] = 1;
}

// ---------------------------------------------------------------------------
// Predicated edge step: slot handles edge base+e, clamped into the segment.
// Clamped duplicates hit identical addresses -> TA coalesces, no extra lines.
// v is forced to 0 for out-of-range slots (unconditional load, cndmask).
// ---------------------------------------------------------------------------
#define EDGE_FMA8P(BASE, ACC)                                         \
    {                                                                 \
        int  jj = (BASE) + e;                                         \
        int  jc = (jj < p1) ? jj : (p1 - 1);                          \
        int   c = __builtin_nontemporal_load(col + jc);               \
        float v = __builtin_nontemporal_load(val + jc);               \
        v = (jj < p1) ? v : 0.0f;                                     \
        ushort8v h8 = *(const ushort8v*)(x + (size_t)c * EMB + d);    \
        _Pragma("unroll")                                             \
        for (int q = 0; q < 8; ++q) ACC[q] += v * bf2f(h8[q]);        \
    }

#define SLOT_REDUCE(ACC)                                              \
    _Pragma("unroll")                                                 \
    for (int q = 0; q < 8; ++q) {                                     \
        ACC[q] += __shfl_xor(ACC[q], 8, 64);                          \
        ACC[q] += __shfl_xor(ACC[q], 16, 64);                        \
        ACC[q] += __shfl_xor(ACC[q], 32, 64);                        \
    }

// ---------------------------------------------------------------------------
// Full SpMM (bf16 in / bf16 out): one wave per row.
//   e = lane>>3 : edge slot (8 concurrent edges); d = (lane&7)*8 dims.
// Wave-uniform loop, 16 edges in flight, zero branch divergence.
// USE_FLAG: skip rows whose output is never consumed.
// ---------------------------------------------------------------------------
template <bool USE_FLAG>
__global__ __launch_bounds__(256) void spmm_bf16(
        const u16* __restrict__ x, const int* __restrict__ col,
        const float* __restrict__ val, const int* __restrict__ ptr,
        const u32* __restrict__ flag, u16* __restrict__ y) {
    int wave = (int)((blockIdx.x * blockDim.x + threadIdx.x) >> 6);
    int lane = threadIdx.x & 63;
    if (wave >= N_NODES) return;
    if (USE_FLAG && flag[wave] == 0) return;
    int e = lane >> 3;          // 0..7
    int d = (lane & 7) << 3;    // 0,8,...,56

    int p0 = ptr[wave];
    int p1 = ptr[wave + 1];

    float8v a0 = {0,0,0,0,0,0,0,0};
    float8v a1 = {0,0,0,0,0,0,0,0};

    for (int base = p0; base < p1; base += 16) {   // wave-uniform trip count
        EDGE_FMA8P(base,     a0);
        EDGE_FMA8P(base + 8, a1);
    }

    #pragma unroll
    for (int q = 0; q < 8; ++q) a0[q] += a1[q];

    SLOT_REDUCE(a0);

    if (e == 0) {
        ushort8v o;
        #pragma unroll
        for (int q = 0; q < 8; ++q) o[q] = f2bf(a0[q]);
        *(ushort8v*)(y + (size_t)wave * EMB + d) = o;
    }
}

// ---------------------------------------------------------------------------
// Layer-3 SpMM restricted to the 8192 selected rows, fused with output
// accumulation: out[slot] += 0.25 * (A * x)[row(slot)].
// ---------------------------------------------------------------------------
__global__ __launch_bounds__(256) void spmm_bf16_sel(
        const u16* __restrict__ x, const int* __restrict__ col,
        const float* __restrict__ val, const int* __restrict__ ptr,
        const int* __restrict__ users, const int* __restrict__ items,
        float* __restrict__ out) {
    int slot = (int)((blockIdx.x * blockDim.x + threadIdx.x) >> 6);
    if (slot >= 2 * BATCH) return;
    int lane = threadIdx.x & 63;
    int e = lane >> 3;
    int d = (lane & 7) << 3;

    int row = (slot < BATCH) ? users[slot] : (items[slot - BATCH] + USER_COUNT);
    int p0 = ptr[row];
    int p1 = ptr[row + 1];

    float8v a0 = {0,0,0,0,0,0,0,0};
    float8v a1 = {0,0,0,0,0,0,0,0};

    for (int base = p0; base < p1; base += 16) {
        EDGE_FMA8P(base,     a0);
        EDGE_FMA8P(base + 8, a1);
    }

    #pragma unroll
    for (int q = 0; q < 8; ++q) a0[q] += a1[q];

    SLOT_REDUCE(a0);

    if (e == 0) {
        float* o = out + (size_t)slot * EMB + d;
        float4 c0 = *(float4*)o;
        float4 c1 = *(float4*)(o + 4);
        c0.x += 0.25f * a0[0]; c0.y += 0.25f * a0[1];
        c0.z += 0.25f * a0[2]; c0.w += 0.25f * a0[3];
        c1.x += 0.25f * a0[4]; c1.y += 0.25f * a0[5];
        c1.z += 0.25f * a0[6]; c1.w += 0.25f * a0[7];
        *(float4*)o       = c0;
        *(float4*)(o + 4) = c1;
    }
}

// ---------------------------------------------------------------------------
// out = 0.25 * ego[selected]  (exact f32 inputs; first write)
// ---------------------------------------------------------------------------
__global__ void gather_f32(const float* __restrict__ xu,
                           const float* __restrict__ xi,
                           const int* __restrict__ users,
                           const int* __restrict__ items,
                           float* __restrict__ out) {
    int tid = blockIdx.x * blockDim.x + threadIdx.x;
    if (tid >= 2 * BATCH * (EMB / 4)) return;
    int b = tid >> 4;
    int e = (tid & 15) << 2;
    const float* src;
    if (b < BATCH) src = xu + (size_t)users[b] * EMB + e;
    else           src = xi + (size_t)items[b - BATCH] * EMB + e;
    float4 s = *(const float4*)src;
    float4 v = {0.25f * s.x, 0.25f * s.y, 0.25f * s.z, 0.25f * s.w};
    *(float4*)(out + (size_t)b * EMB + e) = v;
}

// ---------------------------------------------------------------------------
// out += 0.25 * h[selected]  (bf16 source)
// ---------------------------------------------------------------------------
__global__ void gather_bf16_add(const u16* __restrict__ h,
                                const int* __restrict__ users,
                                const int* __restrict__ items,
                                float* __restrict__ out) {
    int tid = blockIdx.x * blockDim.x + threadIdx.x;
    if (tid >= 2 * BATCH * (EMB / 4)) return;
    int b = tid >> 4;
    int e = (tid & 15) << 2;
    int row = (b < BATCH) ? users[b] : (items[b - BATCH] + USER_COUNT);
    ushort4 s = *(const ushort4*)(h + (size_t)row * EMB + e);
    float4* o = (float4*)(out + (size_t)b * EMB + e);
    float4 cur = *o;
    cur.x += 0.25f * bf2f(s.x);
    cur.y += 0.25f * bf2f(s.y);
    cur.z += 0.25f * bf2f(s.z);
    cur.w += 0.25f * bf2f(s.w);
    *o = cur;
}

extern "C" void kernel_launch(void* const* d_in, const int* in_sizes, int n_in,
                              void* d_out, int out_size, void* d_ws, size_t ws_size,
                              hipStream_t stream) {
    const float* user_emb = (const float*)d_in[0];
    const float* item_emb = (const float*)d_in[1];
    const int*   adj_row  = (const int*)d_in[2];
    const int*   adj_col  = (const int*)d_in[3];
    const float* adj_val  = (const float*)d_in[4];
    const int*   users    = (const int*)d_in[5];
    const int*   items    = (const int*)d_in[6];
    float*       out      = (float*)d_out;
    const int    nnz      = in_sizes[2];

    char* ws = (char*)d_ws;
    const size_t hbytes = (size_t)N_NODES * EMB * sizeof(u16); // 38.4 MB
    u16* ego16 = (u16*)(ws);
    u16* h1    = (u16*)(ws + hbytes);
    u16* h2    = (u16*)(ws + 2 * hbytes);
    int* ptr   = (int*)(ws + 3 * hbytes);
    u32* flag  = (u32*)(ws + 3 * hbytes + (size_t)(N_NODES + 64) * sizeof(int));

    // 0) clear needed-flags (ws is NOT re-zeroed between timed replays)
    hipMemsetAsync(flag, 0, (size_t)N_NODES * sizeof(u32), stream);

    // 1) row_ptr
    build_row_ptr<<<(nnz + 255) / 256, 256, 0, stream>>>(adj_row, ptr, nnz);

    // 2) ego -> bf16
    {
        const size_t total = (size_t)N_NODES * EMB / 4;
        convert_bf16<<<(unsigned)((total + 255) / 256), 256, 0, stream>>>(
            user_emb, item_emb, ego16);
    }

    // 2b) mark rows whose h2 is consumed
    mark_needed<<<(2 * BATCH + 3) / 4, 256, 0, stream>>>(
        users, items, adj_col, ptr, flag);

    // 3) out = 0.25 * ego[sel]  (exact f32)
    const int gthreads = 2 * BATCH * (EMB / 4);
    gather_f32<<<(gthreads + 255) / 256, 256, 0, stream>>>(
        user_emb, item_emb, users, items, out);

    const int spmm_blocks = (N_NODES + 3) / 4;

    // 4) h1 = A * ego16 ; out += 0.25*h1[sel]
    spmm_bf16<false><<<spmm_blocks, 256, 0, stream>>>(
        ego16, adj_col, adj_val, ptr, nullptr, h1);
    gather_bf16_add<<<(gthreads + 255) / 256, 256, 0, stream>>>(h1, users, items, out);

    // 5) h2 = A * h1 (only needed rows) ; out += 0.25*h2[sel]
    spmm_bf16<true><<<spmm_blocks, 256, 0, stream>>>(
        h1, adj_col, adj_val, ptr, flag, h2);
    gather_bf16_add<<<(gthreads + 255) / 256, 256, 0, stream>>>(h2, users, items, out);

    // 6) out += 0.25 * (A*h2)[sel]   (layer 3 restricted to 8192 rows)
    spmm_bf16_sel<<<(2 * BATCH + 3) / 4, 256, 0, stream>>>(
        h2, adj_col, adj_val, ptr, users, items, out);
}